// Round 5
// baseline (137.474 us; speedup 1.0000x reference)
//
#include <hip/hip_runtime.h>

#define NB 16384
#define XD 784
#define ZD 64
#define KK 64
#define LOG2PI_F 1.8378770664093453f

typedef __attribute__((ext_vector_type(8))) short short8;
typedef __attribute__((ext_vector_type(4))) float floatx4;

// ws layout (bytes):
//   [0      , 100352) : Wt[784][64] bf16  (transposed decoder weight)
//   [100352 , 108544) : Bi2[64][64] bf16  (0.5*exp(-2*plog))
//   [108544 , 116736) : Bm1[64][64] bf16  (pmu * i2)
//   [116736 , 116992) : Sk[64]  f32  (sum_v plog[k][v])
//   [116992 , 117248) : Gk[64]  f32  (sum_v pmu^2 * i2)
//   [117248 , 121344) : dec_p[1024] f32 per-wave partials
//   [121344 , 125440) : kly_p[1024]
//   [125440 , 129536) : klz_p[1024]
// No atomics; every slot written unconditionally each call.

__device__ __forceinline__ float wave_sum(float x) {
    #pragma unroll
    for (int o = 32; o > 0; o >>= 1) x += __shfl_xor(x, o, 64);
    return x;
}

__device__ __forceinline__ unsigned short f2bf(float f) {
    unsigned u = __float_as_uint(f);
    unsigned r = (u + 0x7FFF + ((u >> 16) & 1)) >> 16;  // RNE
    return (unsigned short)r;
}

__device__ __forceinline__ unsigned int pack2(float a, float b) {
    return (unsigned int)f2bf(a) | ((unsigned int)f2bf(b) << 16);
}

__device__ __forceinline__ short8 pack8(const float* v) {
    short8 r;
    unsigned int* p = (unsigned int*)&r;
    p[0] = pack2(v[0], v[1]);
    p[1] = pack2(v[2], v[3]);
    p[2] = pack2(v[4], v[5]);
    p[3] = pack2(v[6], v[7]);
    return r;
}

// blocks 0..195: Wt transpose. block 196: B tables + Sk/Gk.
__global__ __launch_bounds__(256) void prep_kernel(
    const float* __restrict__ W, const float* __restrict__ pmu_g,
    const float* __restrict__ plog_g, unsigned short* __restrict__ Wt,
    unsigned short* __restrict__ Bi2, unsigned short* __restrict__ Bm1,
    float* __restrict__ Sk, float* __restrict__ Gk)
{
    const int tid = threadIdx.x;
    if (blockIdx.x < 196) {
        int idx = blockIdx.x * 256 + tid;          // < 50176 exactly
        int k = idx / XD;
        int n = idx - k * XD;
        Wt[n * ZD + k] = f2bf(W[idx]);
        return;
    }
    // B tables: k = tid>>2 (0..63), q = tid&3 covers 16 v each
    const int k  = tid >> 2;
    const int q  = tid & 3;
    const int v0 = q * 16;
    float s = 0.f, g = 0.f;
    unsigned int* pi2 = (unsigned int*)&Bi2[k * 64 + v0];
    unsigned int* pm1 = (unsigned int*)&Bm1[k * 64 + v0];
    #pragma unroll
    for (int i = 0; i < 4; ++i) {
        float4 mu4 = *(const float4*)&pmu_g[k * 64 + v0 + 4 * i];
        float4 lg4 = *(const float4*)&plog_g[k * 64 + v0 + 4 * i];
        float m0[4] = {mu4.x, mu4.y, mu4.z, mu4.w};
        float l0[4] = {lg4.x, lg4.y, lg4.z, lg4.w};
        float i2v[4], m1v[4];
        #pragma unroll
        for (int j = 0; j < 4; ++j) {
            float i2 = 0.5f * __expf(-2.f * l0[j]);
            i2v[j] = i2;
            m1v[j] = m0[j] * i2;
            g = fmaf(m0[j] * m0[j], i2, g);
            s += l0[j];
        }
        pi2[i * 2 + 0] = pack2(i2v[0], i2v[1]);
        pi2[i * 2 + 1] = pack2(i2v[2], i2v[3]);
        pm1[i * 2 + 0] = pack2(m1v[0], m1v[1]);
        pm1[i * 2 + 1] = pack2(m1v[2], m1v[3]);
    }
    s += __shfl_xor(s, 1, 64);
    s += __shfl_xor(s, 2, 64);
    g += __shfl_xor(g, 1, 64);
    g += __shfl_xor(g, 2, 64);
    if (q == 0) { Sk[k] = s; Gk[k] = g; }
}

// Fused mixture + decoder. 64 rows/block, 4 independent waves (16 rows each).
// No LDS, no barriers: A-fragments computed per-lane from global loads;
// B tables / Wt from ws (L2-hot). Softmax via shuffles. Per-wave partial stores.
__global__ __launch_bounds__(256) void fused_kernel(
    const float* __restrict__ x, const float* __restrict__ pi,
    const float* __restrict__ qmu, const float* __restrict__ qls,
    const float* __restrict__ eps,
    const unsigned short* __restrict__ Bi2, const unsigned short* __restrict__ Bm1,
    const float* __restrict__ Sk, const float* __restrict__ Gk,
    const unsigned short* __restrict__ Wt, const float* __restrict__ bd,
    float* __restrict__ dec_p, float* __restrict__ kly_p, float* __restrict__ klz_p)
{
    const int tid   = threadIdx.x;
    const int lane  = tid & 63;
    const int wid   = tid >> 6;
    const int mm    = lane & 15;
    const int quad  = lane >> 4;
    const int row0  = blockIdx.x * 64;
    const int crow0 = row0 + wid * 16;          // wave's first C-row
    const int arow  = crow0 + mm;               // this lane's A-row
    const int v0    = quad * 8;
    const int v1    = 32 + quad * 8;

    // ---- A-side: per-lane global loads, register compute, pack fragments ----
    float mu[16], ls[16], ep[16];
    *(float4*)&mu[0]  = *(const float4*)&qmu[arow * 64 + v0];
    *(float4*)&mu[4]  = *(const float4*)&qmu[arow * 64 + v0 + 4];
    *(float4*)&mu[8]  = *(const float4*)&qmu[arow * 64 + v1];
    *(float4*)&mu[12] = *(const float4*)&qmu[arow * 64 + v1 + 4];
    *(float4*)&ls[0]  = *(const float4*)&qls[arow * 64 + v0];
    *(float4*)&ls[4]  = *(const float4*)&qls[arow * 64 + v0 + 4];
    *(float4*)&ls[8]  = *(const float4*)&qls[arow * 64 + v1];
    *(float4*)&ls[12] = *(const float4*)&qls[arow * 64 + v1 + 4];
    *(float4*)&ep[0]  = *(const float4*)&eps[arow * 64 + v0];
    *(float4*)&ep[4]  = *(const float4*)&eps[arow * 64 + v0 + 4];
    *(float4*)&ep[8]  = *(const float4*)&eps[arow * 64 + v1];
    *(float4*)&ep[12] = *(const float4*)&eps[arow * 64 + v1 + 4];

    float zf[16], zz[16], zm[16], q2[16], qm[16];
    float sls = 0.f;
    #pragma unroll
    for (int j = 0; j < 16; ++j) {
        float qs = __expf(ls[j]);
        float z  = fmaf(qs, ep[j], mu[j]);
        zf[j] = z;
        zz[j] = z * z;
        zm[j] = -2.f * z;
        q2[j] = fmaf(mu[j], mu[j], qs * qs);
        qm[j] = -2.f * mu[j];
        sls += ls[j];
    }
    // full row-sum of qls for row arow (uniform across the 4 quads holding mm)
    sls += __shfl_xor(sls, 16, 64);
    sls += __shfl_xor(sls, 32, 64);

    const short8 az2_0 = pack8(&zz[0]), az2_1 = pack8(&zz[8]);
    const short8 azm_0 = pack8(&zm[0]), azm_1 = pack8(&zm[8]);
    const short8 aq2_0 = pack8(&q2[0]), aq2_1 = pack8(&q2[8]);
    const short8 aqm_0 = pack8(&qm[0]), aqm_1 = pack8(&qm[8]);
    const short8 af0   = pack8(&zf[0]), af1   = pack8(&zf[8]);  // decoder A

    // ---- B-side: ws tables (L2-hot) + per-k scalars + pi prefetch ----
    short8 bi[4][2], bm[4][2];
    float skv[4], gkv[4];
    #pragma unroll
    for (int t = 0; t < 4; ++t) {
        const int kc = t * 16 + mm;
        bi[t][0] = *(const short8*)&Bi2[kc * 64 + v0];
        bi[t][1] = *(const short8*)&Bi2[kc * 64 + v1];
        bm[t][0] = *(const short8*)&Bm1[kc * 64 + v0];
        bm[t][1] = *(const short8*)&Bm1[kc * 64 + v1];
        skv[t] = Sk[kc];
        gkv[t] = Gk[kc];
    }
    float pv[4][4];
    #pragma unroll
    for (int t = 0; t < 4; ++t)
        #pragma unroll
        for (int r = 0; r < 4; ++r)
            pv[t][r] = pi[(crow0 + quad * 4 + r) * 64 + t * 16 + mm];

    // ---- mixture MFMAs ----
    floatx4 acc_a[4], acc_c[4];
    #pragma unroll
    for (int t = 0; t < 4; ++t) {
        floatx4 ca = {0.f, 0.f, 0.f, 0.f};
        ca = __builtin_amdgcn_mfma_f32_16x16x32_bf16(az2_0, bi[t][0], ca, 0, 0, 0);
        ca = __builtin_amdgcn_mfma_f32_16x16x32_bf16(az2_1, bi[t][1], ca, 0, 0, 0);
        ca = __builtin_amdgcn_mfma_f32_16x16x32_bf16(azm_0, bm[t][0], ca, 0, 0, 0);
        ca = __builtin_amdgcn_mfma_f32_16x16x32_bf16(azm_1, bm[t][1], ca, 0, 0, 0);
        acc_a[t] = ca;
        floatx4 cc = {0.f, 0.f, 0.f, 0.f};
        cc = __builtin_amdgcn_mfma_f32_16x16x32_bf16(aq2_0, bi[t][0], cc, 0, 0, 0);
        cc = __builtin_amdgcn_mfma_f32_16x16x32_bf16(aq2_1, bi[t][1], cc, 0, 0, 0);
        cc = __builtin_amdgcn_mfma_f32_16x16x32_bf16(aqm_0, bm[t][0], cc, 0, 0, 0);
        cc = __builtin_amdgcn_mfma_f32_16x16x32_bf16(aqm_1, bm[t][1], cc, 0, 0, 0);
        acc_c[t] = cc;
    }

    // ---- mixture epilogue (softmax over k via shuffles) ----
    float comp[4][4], pz[4][4];
    #pragma unroll
    for (int t = 0; t < 4; ++t) {
        const float ck = -skv[t] - 32.0f * LOG2PI_F;
        #pragma unroll
        for (int r = 0; r < 4; ++r) {
            comp[t][r] = ck - (acc_a[t][r] + gkv[t]);
            pz[t][r] = comp[t][r] + __logf(pv[t][r]);
        }
    }

    float kly = 0.f, klz = 0.f;
    #pragma unroll
    for (int r = 0; r < 4; ++r) {
        float mx = fmaxf(fmaxf(pz[0][r], pz[1][r]), fmaxf(pz[2][r], pz[3][r]));
        #pragma unroll
        for (int o = 1; o <= 8; o <<= 1) mx = fmaxf(mx, __shfl_xor(mx, o, 64));
        float e[4];
        float s = 0.f;
        #pragma unroll
        for (int t = 0; t < 4; ++t) { e[t] = __expf(pz[t][r] - mx); s += e[t]; }
        #pragma unroll
        for (int o = 1; o <= 8; o <<= 1) s += __shfl_xor(s, o, 64);
        const float lse = mx + __logf(s);
        const float inv = __frcp_rn(s);
        const float sqr = __shfl(sls, quad * 4 + r, 64);  // row sum for row crow0+quad*4+r
        #pragma unroll
        for (int t = 0; t < 4; ++t) {
            const float p = e[t] * inv;
            kly = fmaf(p, comp[t][r] - lse, kly);
            klz = fmaf(p, skv[t] - sqr + acc_c[t][r] + gkv[t] - 32.0f, klz);
        }
    }

    kly = wave_sum(kly);
    klz = wave_sum(klz);
    if (lane == 0) {
        kly_p[blockIdx.x * 4 + wid] = kly;
        klz_p[blockIdx.x * 4 + wid] = klz;
    }

    // ---- decoder phase: this wave's 16 rows x all 49 column tiles ----
    const int xrow = (crow0 + quad * 4) * XD;
    float xa0, xa1, xa2, xa3, bb;
    short8 w0, w1;
    {
        const int col = mm;
        xa0 = x[xrow + 0 * XD + col];
        xa1 = x[xrow + 1 * XD + col];
        xa2 = x[xrow + 2 * XD + col];
        xa3 = x[xrow + 3 * XD + col];
        bb  = bd[col];
        w0  = *(const short8*)&Wt[col * 64 + v0];
        w1  = *(const short8*)&Wt[col * 64 + v1];
    }

    float accl = 0.f;
    #pragma unroll 1
    for (int t = 0; t < 49; ++t) {
        const float cx0 = xa0, cx1 = xa1, cx2 = xa2, cx3 = xa3, cb = bb;
        const short8 cw0 = w0, cw1 = w1;
        if (t + 1 < 49) {
            const int col = (t + 1) * 16 + mm;
            xa0 = x[xrow + 0 * XD + col];
            xa1 = x[xrow + 1 * XD + col];
            xa2 = x[xrow + 2 * XD + col];
            xa3 = x[xrow + 3 * XD + col];
            bb  = bd[col];
            w0  = *(const short8*)&Wt[col * 64 + v0];
            w1  = *(const short8*)&Wt[col * 64 + v1];
        }
        floatx4 c = {0.f, 0.f, 0.f, 0.f};
        c = __builtin_amdgcn_mfma_f32_16x16x32_bf16(af0, cw0, c, 0, 0, 0);
        c = __builtin_amdgcn_mfma_f32_16x16x32_bf16(af1, cw1, c, 0, 0, 0);
        float d0 = cx0 - (c[0] + cb);
        float d1 = cx1 - (c[1] + cb);
        float d2 = cx2 - (c[2] + cb);
        float d3 = cx3 - (c[3] + cb);
        accl = fmaf(d0, d0, accl);
        accl = fmaf(d1, d1, accl);
        accl = fmaf(d2, d2, accl);
        accl = fmaf(d3, d3, accl);
    }

    accl = wave_sum(accl);
    if (lane == 0) dec_p[blockIdx.x * 4 + wid] = -0.5f * accl;
}

// Single-block reduction of 3x1024 partials -> elbo.
__global__ __launch_bounds__(256) void finalize_kernel(
    const float* __restrict__ dec_p, const float* __restrict__ kly_p,
    const float* __restrict__ klz_p, float* __restrict__ out)
{
    __shared__ double s0[256], s1[256], s2[256];
    const int tid = threadIdx.x;
    double a0 = 0.0, a1 = 0.0, a2 = 0.0;
    #pragma unroll
    for (int i = 0; i < 4; ++i) {
        a0 += (double)dec_p[tid + 256 * i];
        a1 += (double)kly_p[tid + 256 * i];
        a2 += (double)klz_p[tid + 256 * i];
    }
    s0[tid] = a0; s1[tid] = a1; s2[tid] = a2;
    __syncthreads();
    #pragma unroll
    for (int off = 128; off > 0; off >>= 1) {
        if (tid < off) {
            s0[tid] += s0[tid + off];
            s1[tid] += s1[tid + off];
            s2[tid] += s2[tid + off];
        }
        __syncthreads();
    }
    if (tid == 0) {
        double lpx = s0[0] - 0.5 * 1.8378770664093453 * (double)NB * (double)XD;
        out[0] = (float)((lpx - s1[0] - s2[0]) / (double)NB);
    }
}

extern "C" void kernel_launch(void* const* d_in, const int* in_sizes, int n_in,
                              void* d_out, int out_size, void* d_ws, size_t ws_size,
                              hipStream_t stream) {
    const float* x    = (const float*)d_in[0];
    const float* pi   = (const float*)d_in[1];
    const float* qmu  = (const float*)d_in[2];
    const float* qls  = (const float*)d_in[3];
    const float* eps  = (const float*)d_in[4];
    const float* pmu  = (const float*)d_in[5];
    const float* plog = (const float*)d_in[6];
    const float* W    = (const float*)d_in[7];
    const float* bd   = (const float*)d_in[8];
    float* out = (float*)d_out;

    char* ws = (char*)d_ws;
    unsigned short* Wt  = (unsigned short*)(ws);
    unsigned short* Bi2 = (unsigned short*)(ws + 100352);
    unsigned short* Bm1 = (unsigned short*)(ws + 108544);
    float* Sk    = (float*)(ws + 116736);
    float* Gk    = (float*)(ws + 116992);
    float* dec_p = (float*)(ws + 117248);
    float* kly_p = (float*)(ws + 121344);
    float* klz_p = (float*)(ws + 125440);

    prep_kernel<<<197, 256, 0, stream>>>(W, pmu, plog, Wt, Bi2, Bm1, Sk, Gk);
    fused_kernel<<<NB / 64, 256, 0, stream>>>(x, pi, qmu, qls, eps,
                                              Bi2, Bm1, Sk, Gk, Wt, bd,
                                              dec_p, kly_p, klz_p);
    finalize_kernel<<<1, 256, 0, stream>>>(dec_p, kly_p, klz_p, out);
}

// Round 6
// 129.539 us; speedup vs baseline: 1.0613x; 1.0613x over previous
//
#include <hip/hip_runtime.h>

#define NB 16384
#define XD 784
#define ZD 64
#define KK 64
#define LOG2PI_F 1.8378770664093453f

typedef __attribute__((ext_vector_type(8))) short short8;
typedef __attribute__((ext_vector_type(4))) float floatx4;

// ws layout (bytes):
//   [0      , 100352) : Wt[784][64] bf16  (transposed decoder weight)
//   [100352 , 108544) : Bi2[64][64] bf16  (0.5*exp(-2*plog))
//   [108544 , 116736) : Bm1[64][64] bf16  (pmu * i2)
//   [116736 , 116992) : Sk[64]  f32
//   [116992 , 117248) : Gk[64]  f32
//   [117248 , 133632) : dec_p[4096] f32  (per-wave partials)
//   [133632 , 137728) : kly_p[1024] f32  (per-block)
//   [137728 , 141824) : klz_p[1024] f32  (per-block)
// No atomics; every slot written unconditionally each call.

__device__ __forceinline__ float wave_sum(float x) {
    #pragma unroll
    for (int o = 32; o > 0; o >>= 1) x += __shfl_xor(x, o, 64);
    return x;
}

__device__ __forceinline__ unsigned short f2bf(float f) {
    unsigned u = __float_as_uint(f);
    unsigned r = (u + 0x7FFF + ((u >> 16) & 1)) >> 16;  // RNE
    return (unsigned short)r;
}

__device__ __forceinline__ unsigned int pack2(float a, float b) {
    return (unsigned int)f2bf(a) | ((unsigned int)f2bf(b) << 16);
}

__device__ __forceinline__ short8 pack8(const float* v) {
    short8 r;
    unsigned int* p = (unsigned int*)&r;
    p[0] = pack2(v[0], v[1]);
    p[1] = pack2(v[2], v[3]);
    p[2] = pack2(v[4], v[5]);
    p[3] = pack2(v[6], v[7]);
    return r;
}

// blocks 0..195: Wt transpose. block 196: B tables + Sk/Gk.
__global__ __launch_bounds__(256) void prep_kernel(
    const float* __restrict__ W, const float* __restrict__ pmu_g,
    const float* __restrict__ plog_g, unsigned short* __restrict__ Wt,
    unsigned short* __restrict__ Bi2, unsigned short* __restrict__ Bm1,
    float* __restrict__ Sk, float* __restrict__ Gk)
{
    const int tid = threadIdx.x;
    if (blockIdx.x < 196) {
        int idx = blockIdx.x * 256 + tid;          // < 50176 exactly
        int k = idx / XD;
        int n = idx - k * XD;
        Wt[n * ZD + k] = f2bf(W[idx]);
        return;
    }
    const int k  = tid >> 2;
    const int q  = tid & 3;
    const int v0 = q * 16;
    float s = 0.f, g = 0.f;
    unsigned int* pi2 = (unsigned int*)&Bi2[k * 64 + v0];
    unsigned int* pm1 = (unsigned int*)&Bm1[k * 64 + v0];
    #pragma unroll
    for (int i = 0; i < 4; ++i) {
        float4 mu4 = *(const float4*)&pmu_g[k * 64 + v0 + 4 * i];
        float4 lg4 = *(const float4*)&plog_g[k * 64 + v0 + 4 * i];
        float m0[4] = {mu4.x, mu4.y, mu4.z, mu4.w};
        float l0[4] = {lg4.x, lg4.y, lg4.z, lg4.w};
        float i2v[4], m1v[4];
        #pragma unroll
        for (int j = 0; j < 4; ++j) {
            float i2 = 0.5f * __expf(-2.f * l0[j]);
            i2v[j] = i2;
            m1v[j] = m0[j] * i2;
            g = fmaf(m0[j] * m0[j], i2, g);
            s += l0[j];
        }
        pi2[i * 2 + 0] = pack2(i2v[0], i2v[1]);
        pi2[i * 2 + 1] = pack2(i2v[2], i2v[3]);
        pm1[i * 2 + 0] = pack2(m1v[0], m1v[1]);
        pm1[i * 2 + 1] = pack2(m1v[2], m1v[3]);
    }
    s += __shfl_xor(s, 1, 64);
    s += __shfl_xor(s, 2, 64);
    g += __shfl_xor(g, 1, 64);
    g += __shfl_xor(g, 2, 64);
    if (q == 0) { Sk[k] = s; Gk[k] = g; }
}

// Fused mixture+decoder: 16 rows/block, 4 waves share the rows.
// Wave 3 additionally computes the mixture (MFMA quadratics + softmax + KLs).
// All waves split the 49 decoder column tiles (t % 4 == wid).
// No LDS, no barriers; per-wave/per-block partial stores, no atomics.
__global__ __launch_bounds__(256) void fused_kernel(
    const float* __restrict__ x, const float* __restrict__ pi,
    const float* __restrict__ qmu, const float* __restrict__ qls,
    const float* __restrict__ eps,
    const unsigned short* __restrict__ Bi2, const unsigned short* __restrict__ Bm1,
    const float* __restrict__ Sk, const float* __restrict__ Gk,
    const unsigned short* __restrict__ Wt, const float* __restrict__ bd,
    float* __restrict__ dec_p, float* __restrict__ kly_p, float* __restrict__ klz_p)
{
    const int tid   = threadIdx.x;
    const int lane  = tid & 63;
    const int wid   = tid >> 6;
    const int mm    = lane & 15;
    const int quad  = lane >> 4;
    const int row0  = blockIdx.x * 16;
    const int arow  = row0 + mm;
    const int v0    = quad * 8;
    const int v1    = 32 + quad * 8;

    // ---- A-side loads (same rows for all 4 waves; L1/L2-hot) ----
    float mu[16], ls[16], ep[16];
    *(float4*)&mu[0]  = *(const float4*)&qmu[arow * 64 + v0];
    *(float4*)&mu[4]  = *(const float4*)&qmu[arow * 64 + v0 + 4];
    *(float4*)&mu[8]  = *(const float4*)&qmu[arow * 64 + v1];
    *(float4*)&mu[12] = *(const float4*)&qmu[arow * 64 + v1 + 4];
    *(float4*)&ls[0]  = *(const float4*)&qls[arow * 64 + v0];
    *(float4*)&ls[4]  = *(const float4*)&qls[arow * 64 + v0 + 4];
    *(float4*)&ls[8]  = *(const float4*)&qls[arow * 64 + v1];
    *(float4*)&ls[12] = *(const float4*)&qls[arow * 64 + v1 + 4];
    *(float4*)&ep[0]  = *(const float4*)&eps[arow * 64 + v0];
    *(float4*)&ep[4]  = *(const float4*)&eps[arow * 64 + v0 + 4];
    *(float4*)&ep[8]  = *(const float4*)&eps[arow * 64 + v1];
    *(float4*)&ep[12] = *(const float4*)&eps[arow * 64 + v1 + 4];

    float zf[16], ls_sum = 0.f;
    float qsv[16];
    #pragma unroll
    for (int j = 0; j < 16; ++j) {
        qsv[j] = __expf(ls[j]);
        zf[j]  = fmaf(qsv[j], ep[j], mu[j]);
        ls_sum += ls[j];
    }
    const short8 af0 = pack8(&zf[0]), af1 = pack8(&zf[8]);  // decoder A-frag

    // ---- mixture (wave 3 only; wave-uniform branch) ----
    if (wid == 3) {
        float zz[16], zm[16], q2[16], qm[16];
        #pragma unroll
        for (int j = 0; j < 16; ++j) {
            zz[j] = zf[j] * zf[j];
            zm[j] = -2.f * zf[j];
            q2[j] = fmaf(mu[j], mu[j], qsv[j] * qsv[j]);
            qm[j] = -2.f * mu[j];
        }
        float sls = ls_sum;
        sls += __shfl_xor(sls, 16, 64);
        sls += __shfl_xor(sls, 32, 64);

        const short8 az2_0 = pack8(&zz[0]), az2_1 = pack8(&zz[8]);
        const short8 azm_0 = pack8(&zm[0]), azm_1 = pack8(&zm[8]);
        const short8 aq2_0 = pack8(&q2[0]), aq2_1 = pack8(&q2[8]);
        const short8 aqm_0 = pack8(&qm[0]), aqm_1 = pack8(&qm[8]);

        short8 bi[4][2], bm[4][2];
        float skv[4], gkv[4];
        #pragma unroll
        for (int t = 0; t < 4; ++t) {
            const int kc = t * 16 + mm;
            bi[t][0] = *(const short8*)&Bi2[kc * 64 + v0];
            bi[t][1] = *(const short8*)&Bi2[kc * 64 + v1];
            bm[t][0] = *(const short8*)&Bm1[kc * 64 + v0];
            bm[t][1] = *(const short8*)&Bm1[kc * 64 + v1];
            skv[t] = Sk[kc];
            gkv[t] = Gk[kc];
        }
        float pv[4][4];
        #pragma unroll
        for (int t = 0; t < 4; ++t)
            #pragma unroll
            for (int r = 0; r < 4; ++r)
                pv[t][r] = pi[(row0 + quad * 4 + r) * 64 + t * 16 + mm];

        floatx4 acc_a[4], acc_c[4];
        #pragma unroll
        for (int t = 0; t < 4; ++t) {
            floatx4 ca = {0.f, 0.f, 0.f, 0.f};
            ca = __builtin_amdgcn_mfma_f32_16x16x32_bf16(az2_0, bi[t][0], ca, 0, 0, 0);
            ca = __builtin_amdgcn_mfma_f32_16x16x32_bf16(az2_1, bi[t][1], ca, 0, 0, 0);
            ca = __builtin_amdgcn_mfma_f32_16x16x32_bf16(azm_0, bm[t][0], ca, 0, 0, 0);
            ca = __builtin_amdgcn_mfma_f32_16x16x32_bf16(azm_1, bm[t][1], ca, 0, 0, 0);
            acc_a[t] = ca;
            floatx4 cc = {0.f, 0.f, 0.f, 0.f};
            cc = __builtin_amdgcn_mfma_f32_16x16x32_bf16(aq2_0, bi[t][0], cc, 0, 0, 0);
            cc = __builtin_amdgcn_mfma_f32_16x16x32_bf16(aq2_1, bi[t][1], cc, 0, 0, 0);
            cc = __builtin_amdgcn_mfma_f32_16x16x32_bf16(aqm_0, bm[t][0], cc, 0, 0, 0);
            cc = __builtin_amdgcn_mfma_f32_16x16x32_bf16(aqm_1, bm[t][1], cc, 0, 0, 0);
            acc_c[t] = cc;
        }

        float comp[4][4], pz[4][4];
        #pragma unroll
        for (int t = 0; t < 4; ++t) {
            const float ck = -skv[t] - 32.0f * LOG2PI_F;
            #pragma unroll
            for (int r = 0; r < 4; ++r) {
                comp[t][r] = ck - (acc_a[t][r] + gkv[t]);
                pz[t][r] = comp[t][r] + __logf(pv[t][r]);
            }
        }

        float kly = 0.f, klz = 0.f;
        #pragma unroll
        for (int r = 0; r < 4; ++r) {
            float mx = fmaxf(fmaxf(pz[0][r], pz[1][r]), fmaxf(pz[2][r], pz[3][r]));
            #pragma unroll
            for (int o = 1; o <= 8; o <<= 1) mx = fmaxf(mx, __shfl_xor(mx, o, 64));
            float e[4];
            float s = 0.f;
            #pragma unroll
            for (int t = 0; t < 4; ++t) { e[t] = __expf(pz[t][r] - mx); s += e[t]; }
            #pragma unroll
            for (int o = 1; o <= 8; o <<= 1) s += __shfl_xor(s, o, 64);
            const float lse = mx + __logf(s);
            const float inv = __frcp_rn(s);
            const float sqr = __shfl(sls, quad * 4 + r, 64);
            #pragma unroll
            for (int t = 0; t < 4; ++t) {
                const float p = e[t] * inv;
                kly = fmaf(p, comp[t][r] - lse, kly);
                klz = fmaf(p, skv[t] - sqr + acc_c[t][r] + gkv[t] - 32.0f, klz);
            }
        }

        kly = wave_sum(kly);
        klz = wave_sum(klz);
        if (lane == 0) {
            kly_p[blockIdx.x] = kly;
            klz_p[blockIdx.x] = klz;
        }
    }

    // ---- decoder phase: wave wid handles tiles t = wid, wid+4, ..., <49 ----
    const int xrow = (row0 + quad * 4) * XD;
    float xa0, xa1, xa2, xa3, bb;
    short8 w0, w1;
    {
        const int col = wid * 16 + mm;
        xa0 = x[xrow + 0 * XD + col];
        xa1 = x[xrow + 1 * XD + col];
        xa2 = x[xrow + 2 * XD + col];
        xa3 = x[xrow + 3 * XD + col];
        bb  = bd[col];
        w0  = *(const short8*)&Wt[col * 64 + v0];
        w1  = *(const short8*)&Wt[col * 64 + v1];
    }

    float accl = 0.f;
    #pragma unroll 1
    for (int t = wid; t < 49; t += 4) {
        const float cx0 = xa0, cx1 = xa1, cx2 = xa2, cx3 = xa3, cb = bb;
        const short8 cw0 = w0, cw1 = w1;
        const int tn = t + 4;
        if (tn < 49) {
            const int col = tn * 16 + mm;
            xa0 = x[xrow + 0 * XD + col];
            xa1 = x[xrow + 1 * XD + col];
            xa2 = x[xrow + 2 * XD + col];
            xa3 = x[xrow + 3 * XD + col];
            bb  = bd[col];
            w0  = *(const short8*)&Wt[col * 64 + v0];
            w1  = *(const short8*)&Wt[col * 64 + v1];
        }
        floatx4 c = {0.f, 0.f, 0.f, 0.f};
        c = __builtin_amdgcn_mfma_f32_16x16x32_bf16(af0, cw0, c, 0, 0, 0);
        c = __builtin_amdgcn_mfma_f32_16x16x32_bf16(af1, cw1, c, 0, 0, 0);
        float d0 = cx0 - (c[0] + cb);
        float d1 = cx1 - (c[1] + cb);
        float d2 = cx2 - (c[2] + cb);
        float d3 = cx3 - (c[3] + cb);
        accl = fmaf(d0, d0, accl);
        accl = fmaf(d1, d1, accl);
        accl = fmaf(d2, d2, accl);
        accl = fmaf(d3, d3, accl);
    }

    accl = wave_sum(accl);
    if (lane == 0) dec_p[blockIdx.x * 4 + wid] = -0.5f * accl;
}

// Single-block reduction: 4096 dec + 1024 kly + 1024 klz partials -> elbo.
__global__ __launch_bounds__(256) void finalize_kernel(
    const float* __restrict__ dec_p, const float* __restrict__ kly_p,
    const float* __restrict__ klz_p, float* __restrict__ out)
{
    __shared__ double s0[256], s1[256], s2[256];
    const int tid = threadIdx.x;
    double a0 = 0.0, a1 = 0.0, a2 = 0.0;
    #pragma unroll
    for (int i = 0; i < 16; ++i) a0 += (double)dec_p[tid + 256 * i];
    #pragma unroll
    for (int i = 0; i < 4; ++i) {
        a1 += (double)kly_p[tid + 256 * i];
        a2 += (double)klz_p[tid + 256 * i];
    }
    s0[tid] = a0; s1[tid] = a1; s2[tid] = a2;
    __syncthreads();
    #pragma unroll
    for (int off = 128; off > 0; off >>= 1) {
        if (tid < off) {
            s0[tid] += s0[tid + off];
            s1[tid] += s1[tid + off];
            s2[tid] += s2[tid + off];
        }
        __syncthreads();
    }
    if (tid == 0) {
        double lpx = s0[0] - 0.5 * 1.8378770664093453 * (double)NB * (double)XD;
        out[0] = (float)((lpx - s1[0] - s2[0]) / (double)NB);
    }
}

extern "C" void kernel_launch(void* const* d_in, const int* in_sizes, int n_in,
                              void* d_out, int out_size, void* d_ws, size_t ws_size,
                              hipStream_t stream) {
    const float* x    = (const float*)d_in[0];
    const float* pi   = (const float*)d_in[1];
    const float* qmu  = (const float*)d_in[2];
    const float* qls  = (const float*)d_in[3];
    const float* eps  = (const float*)d_in[4];
    const float* pmu  = (const float*)d_in[5];
    const float* plog = (const float*)d_in[6];
    const float* W    = (const float*)d_in[7];
    const float* bd   = (const float*)d_in[8];
    float* out = (float*)d_out;

    char* ws = (char*)d_ws;
    unsigned short* Wt  = (unsigned short*)(ws);
    unsigned short* Bi2 = (unsigned short*)(ws + 100352);
    unsigned short* Bm1 = (unsigned short*)(ws + 108544);
    float* Sk    = (float*)(ws + 116736);
    float* Gk    = (float*)(ws + 116992);
    float* dec_p = (float*)(ws + 117248);   // 4096 floats
    float* kly_p = (float*)(ws + 133632);   // 1024 floats
    float* klz_p = (float*)(ws + 137728);   // 1024 floats

    prep_kernel<<<197, 256, 0, stream>>>(W, pmu, plog, Wt, Bi2, Bm1, Sk, Gk);
    fused_kernel<<<NB / 16, 256, 0, stream>>>(x, pi, qmu, qls, eps,
                                              Bi2, Bm1, Sk, Gk, Wt, bd,
                                              dec_p, kly_p, klz_p);
    finalize_kernel<<<1, 256, 0, stream>>>(dec_p, kly_p, klz_p, out);
}